// Round 9
// baseline (272.199 us; speedup 1.0000x reference)
//
#include <hip/hip_runtime.h>
#include <hip/hip_bf16.h>

#define NN 50000
#define NE 800000
#define HID 128
#define ROWD 68           // x1 LDS pitch in dwords
#define APITCH 136        // node-gemm A-tile pitch in bf16 elems
#define N2 (16*128*8)     // W2p shorts (sigma-K packed)
#define NB_NODE 782       // ceil(NN/64) node-GEMM blocks

typedef float f32x4 __attribute__((ext_vector_type(4)));
typedef short s16x8 __attribute__((ext_vector_type(8)));
typedef unsigned int u32;

__device__ __forceinline__ unsigned short f2bf(float x) {   // RNE
    u32 u = __float_as_uint(x);
    u32 r = (u + 0x7FFFu + ((u >> 16) & 1u)) >> 16;
    return (unsigned short)r;
}
__device__ __forceinline__ float silu_f(float v) {          // no IEEE divide
    float e = __expf(-v);
    return v * __builtin_amdgcn_rcpf(1.f + e);
}
__device__ __forceinline__ u32 pack2bf(float lo, float hi) {   // truncation pack
    return __builtin_amdgcn_perm(__float_as_uint(hi), __float_as_uint(lo), 0x07060302u);
}
__device__ __forceinline__ u32 fuse_silu_pack(u32 a, u32 b, float ea, float wlo, float whi) {
    float xlo = __uint_as_float(a << 16) + __uint_as_float(b << 16) + ea * wlo;
    float xhi = __uint_as_float(a & 0xFFFF0000u) + __uint_as_float(b & 0xFFFF0000u) + ea * whi;
    return pack2bf(silu_f(xlo), silu_f(xhi));
}

// Build one MFMA B-fragment (8 k-values, fixed col n) straight from f32 W1.
// Matches the W1p layout used R4-R8: shorts[kin] = bf16(W1[(kblk*8+kin)*HID + n]).
__device__ __forceinline__ s16x8 frag_from_W1(const float* __restrict__ W1, int kblk, int n) {
    union { s16x8 s; u32 d[4]; } f;
    #pragma unroll
    for (int j = 0; j < 4; ++j) {
        float lo = W1[(size_t)(kblk * 8 + 2 * j    ) * HID + n];
        float hi = W1[(size_t)(kblk * 8 + 2 * j + 1) * HID + n];
        f.d[j] = pack2bf(lo, hi);
    }
    return f.s;
}

// K1: blocks [0, NB_NODE) compute Pa/Pb (node GEMM, W1 fragments built from f32);
//     blocks [NB_NODE, ...) pack W2p (sigma-K, verified R3-R8) and init
//     out = coord * node_mask.
__global__ __launch_bounds__(256) void node_fused(
        const float* __restrict__ h, const float* __restrict__ W1,
        const float* __restrict__ b1, const float* __restrict__ W2,
        const float* __restrict__ coord, const float* __restrict__ node_mask,
        unsigned short* __restrict__ W2p, u32* __restrict__ Pa, u32* __restrict__ Pb,
        float* __restrict__ out) {
    __shared__ unsigned short s_a[64 * APITCH];   // 17408 B (node part only)
    const int tid = threadIdx.x;

    if (blockIdx.x >= NB_NODE) {
        // ---- aux: W2p pack + out init ----
        int base = (blockIdx.x - NB_NODE) * 256 + tid;
        int stride = (gridDim.x - NB_NODE) * 256;
        for (int idx = base; idx < N2 + NN; idx += stride) {
            if (idx < N2) {
                int kblk = idx >> 10;
                int rem  = idx & 1023;
                int n    = rem >> 3;
                int kin  = rem & 7;
                int p    = kblk * 8 + kin;
                int tt   = p >> 1;
                int srow = 32 * (tt >> 4) + (tt & 15) + 16 * (p & 1);
                W2p[idx] = f2bf(W2[srow * HID + n]);
            } else {
                int i = idx - N2;
                float nm = node_mask[i];
                out[i * 3 + 0] = coord[i * 3 + 0] * nm;
                out[i * 3 + 1] = coord[i * 3 + 1] * nm;
                out[i * 3 + 2] = coord[i * 3 + 2] * nm;
            }
        }
        return;
    }

    // ---- node GEMM: Pa = h@W1a + b1, Pb = h@W1b (sigma-paired bf16) ----
    const int m0 = blockIdx.x * 64;
    #pragma unroll
    for (int it = 0; it < 8; ++it) {
        int chunk = it * 256 + tid;
        int r  = chunk >> 5;
        int cc = chunk & 31;
        int row = m0 + r;
        float4 v = {0.f, 0.f, 0.f, 0.f};
        if (row < NN) v = *(const float4*)(h + (size_t)row * HID + cc * 4);
        uint2 pk;
        pk.x = ((u32)f2bf(v.x)) | ((u32)f2bf(v.y) << 16);
        pk.y = ((u32)f2bf(v.z)) | ((u32)f2bf(v.w) << 16);
        *(uint2*)&s_a[r * APITCH + cc * 4] = pk;
    }
    __syncthreads();

    const int lane = tid & 63;
    const int w    = tid >> 6;
    const int q    = lane >> 4;
    const int c16  = lane & 15;
    const int n0   = w * 32 + c16;

    f32x4 accA[4][2], accB[4][2];
    #pragma unroll
    for (int mt = 0; mt < 4; ++mt) {
        accA[mt][0] = f32x4{0.f,0.f,0.f,0.f}; accA[mt][1] = f32x4{0.f,0.f,0.f,0.f};
        accB[mt][0] = f32x4{0.f,0.f,0.f,0.f}; accB[mt][1] = f32x4{0.f,0.f,0.f,0.f};
    }
    #pragma unroll
    for (int ks = 0; ks < 4; ++ks) {
        s16x8 afr[4];
        #pragma unroll
        for (int mt = 0; mt < 4; ++mt)
            afr[mt] = *(const s16x8*)&s_a[(mt * 16 + c16) * APITCH + ks * 32 + q * 8];
        int ka = ks * 4 + q;
        int kb = 16 + ks * 4 + q;
        s16x8 ba0 = frag_from_W1(W1, ka, n0);
        s16x8 ba1 = frag_from_W1(W1, ka, n0 + 16);
        s16x8 bb0 = frag_from_W1(W1, kb, n0);
        s16x8 bb1 = frag_from_W1(W1, kb, n0 + 16);
        #pragma unroll
        for (int mt = 0; mt < 4; ++mt) {
            accA[mt][0] = __builtin_amdgcn_mfma_f32_16x16x32_bf16(afr[mt], ba0, accA[mt][0], 0, 0, 0);
            accA[mt][1] = __builtin_amdgcn_mfma_f32_16x16x32_bf16(afr[mt], ba1, accA[mt][1], 0, 0, 0);
            accB[mt][0] = __builtin_amdgcn_mfma_f32_16x16x32_bf16(afr[mt], bb0, accB[mt][0], 0, 0, 0);
            accB[mt][1] = __builtin_amdgcn_mfma_f32_16x16x32_bf16(afr[mt], bb1, accB[mt][1], 0, 0, 0);
        }
    }
    float b1lo = b1[n0], b1hi = b1[n0 + 16];
    const int d = w * 16 + c16;
    #pragma unroll
    for (int mt = 0; mt < 4; ++mt) {
        #pragma unroll
        for (int r = 0; r < 4; ++r) {
            int m = mt * 16 + q * 4 + r;     // C/D: col=lane&15, row=quad*4+reg
            int row = m0 + m;
            if (row < NN) {
                Pa[(size_t)row * 64 + d] = pack2bf(accA[mt][0][r] + b1lo, accA[mt][1][r] + b1hi);
                Pb[(size_t)row * 64 + d] = pack2bf(accB[mt][0][r], accB[mt][1][r]);
            }
        }
    }
}

// K2: edge kernel — R4's measured-best 64-edge structure (VGPR ~50, occ ~47%)
// with the folded finalize epilogue (verified R8).
__global__ __launch_bounds__(256) void edge_kernel(
        const u32* __restrict__ Pa, const u32* __restrict__ Pb,
        const int* __restrict__ edge_index,
        const float* __restrict__ coord_diff, const float* __restrict__ edge_attr,
        const float* __restrict__ edge_mask, const float* __restrict__ node_mask,
        const unsigned short* __restrict__ W2p, const float* __restrict__ W1,
        const float* __restrict__ b2, const float* __restrict__ W3,
        float* __restrict__ agg) {
    __shared__ u32   s_x1[64 * ROWD];   // 17408 B
    __shared__ float s_phi[256];        // 1024 B

    const int tid  = threadIdx.x;
    const int lane = tid & 63;
    const int w    = tid >> 6;
    const int q    = lane >> 4;
    const int c16  = lane & 15;
    const int n0   = w * 32 + c16;
    const int e0   = blockIdx.x * 64;
    const int c    = tid & 15;          // dword group
    const int rs   = tid >> 4;          // row-sub 0..15

    // fuse constants for dword group c (sigma col map, verified R4-R8)
    const float* W1r = W1 + 256 * HID;
    float w1rlo[4], w1rhi[4];
    #pragma unroll
    for (int i = 0; i < 4; ++i) {
        int dd = c * 4 + i;
        int cl = 32 * (dd >> 4) + (dd & 15);
        w1rlo[i] = W1r[cl];
        w1rhi[i] = W1r[cl + 16];
    }
    const float b2lo = b2[n0], b2hi = b2[n0 + 16];
    const float w3lo = W3[n0], w3hi = W3[n0 + 16];

    // gather Pa[row]+Pb[col] for the tile's 64 edges (4 per 16-lane group)
    #pragma unroll
    for (int it = 0; it < 4; ++it) {
        int m  = it * 16 + rs;
        int e  = e0 + m;
        int ri = edge_index[e];
        int ci = edge_index[NE + e];
        float ea = edge_attr[e];
        uint4 pa = *(const uint4*)(Pa + (size_t)ri * 64 + c * 4);
        uint4 pb = *(const uint4*)(Pb + (size_t)ci * 64 + c * 4);
        uint4 o;
        o.x = fuse_silu_pack(pa.x, pb.x, ea, w1rlo[0], w1rhi[0]);
        o.y = fuse_silu_pack(pa.y, pb.y, ea, w1rlo[1], w1rhi[1]);
        o.z = fuse_silu_pack(pa.z, pb.z, ea, w1rlo[2], w1rhi[2]);
        o.w = fuse_silu_pack(pa.w, pb.w, ea, w1rlo[3], w1rhi[3]);
        *(uint4*)&s_x1[m * ROWD + c * 4] = o;
    }
    __syncthreads();

    // layer 2: [64,128] @ W2p (sigma-K)
    f32x4 acc2[4][2];
    #pragma unroll
    for (int mt = 0; mt < 4; ++mt) {
        acc2[mt][0] = f32x4{0.f,0.f,0.f,0.f};
        acc2[mt][1] = f32x4{0.f,0.f,0.f,0.f};
    }
    #pragma unroll
    for (int ks = 0; ks < 4; ++ks) {
        int kblk = ks * 4 + q;
        s16x8 b0  = *(const s16x8*)(W2p + (size_t)(kblk * HID + n0) * 8);
        s16x8 b1f = *(const s16x8*)(W2p + (size_t)(kblk * HID + n0 + 16) * 8);
        #pragma unroll
        for (int mt = 0; mt < 4; ++mt) {
            s16x8 afr = *(const s16x8*)&s_x1[(mt * 16 + c16) * ROWD + ks * 16 + q * 4];
            acc2[mt][0] = __builtin_amdgcn_mfma_f32_16x16x32_bf16(afr, b0,  acc2[mt][0], 0, 0, 0);
            acc2[mt][1] = __builtin_amdgcn_mfma_f32_16x16x32_bf16(afr, b1f, acc2[mt][1], 0, 0, 0);
        }
    }

    // layer 3: phi = sum_n silu(x2+b2)*W3
    #pragma unroll
    for (int mt = 0; mt < 4; ++mt) {
        float pr[4];
        #pragma unroll
        for (int r = 0; r < 4; ++r) {
            float s0 = silu_f(acc2[mt][0][r] + b2lo);
            float s1 = silu_f(acc2[mt][1][r] + b2hi);
            pr[r] = fmaf(s0, w3lo, s1 * w3hi);
        }
        #pragma unroll
        for (int off = 8; off >= 1; off >>= 1) {
            #pragma unroll
            for (int r = 0; r < 4; ++r) pr[r] += __shfl_xor(pr[r], off);
        }
        if (c16 == 0) {
            #pragma unroll
            for (int r = 0; r < 4; ++r)
                s_phi[(mt * 16 + q * 4 + r) * 4 + w] = pr[r];
        }
    }
    __syncthreads();

    // epilogue with folded finalize: add coord_diff * phi * edge_mask * 0.01 * nm[r]
    if (tid < 64) {
        int e = e0 + tid;
        float phi = s_phi[tid * 4 + 0] + s_phi[tid * 4 + 1]
                  + s_phi[tid * 4 + 2] + s_phi[tid * 4 + 3];
        int r = edge_index[e];
        float scale = phi * edge_mask[e] * 0.01f * node_mask[r];
        atomicAdd(&agg[r * 3 + 0], coord_diff[e * 3 + 0] * scale);
        atomicAdd(&agg[r * 3 + 1], coord_diff[e * 3 + 1] * scale);
        atomicAdd(&agg[r * 3 + 2], coord_diff[e * 3 + 2] * scale);
    }
}

extern "C" void kernel_launch(void* const* d_in, const int* in_sizes, int n_in,
                              void* d_out, int out_size, void* d_ws, size_t ws_size,
                              hipStream_t stream) {
    const float* h          = (const float*)d_in[0];
    const float* coord      = (const float*)d_in[1];
    const int*   edge_index = (const int*)d_in[2];
    const float* coord_diff = (const float*)d_in[3];
    // d_in[4] coord_cross: unused
    const float* edge_attr  = (const float*)d_in[5];
    const float* node_mask  = (const float*)d_in[6];
    const float* edge_mask  = (const float*)d_in[7];
    const float* W1         = (const float*)d_in[8];
    const float* b1         = (const float*)d_in[9];
    const float* W2         = (const float*)d_in[10];
    const float* b2         = (const float*)d_in[11];
    const float* W3         = (const float*)d_in[12];
    float* out = (float*)d_out;

    unsigned short* W2p = (unsigned short*)d_ws;
    u32* Pa = (u32*)(W2p + N2);
    u32* Pb = Pa + (size_t)NN * 64;    // total ~25.6 MB (ws sufficiency proven R4-R8)

    // K1: node GEMM + aux (W2p pack, out init). 782 GEMM blocks + 260 aux blocks.
    const int nb_aux = (N2 + NN + 255) / 256;
    node_fused<<<NB_NODE + nb_aux, 256, 0, stream>>>(h, W1, b1, W2, coord, node_mask,
                                                     W2p, Pa, Pb, out);
    // K2: edges
    edge_kernel<<<NE / 64, 256, 0, stream>>>(Pa, Pb, edge_index, coord_diff, edge_attr,
                                             edge_mask, node_mask, W2p, W1, b2, W3, out);
}